// Round 17
// baseline (932.808 us; speedup 1.0000x reference)
//
#include <hip/hip_runtime.h>
#include <hip/hip_bf16.h>
#include <math.h>

// ---------------- constants ----------------
constexpr float EPSB = 1e-5f;

// slice stage: channel-last padded [81][66][66][16] fp16
constexpr int SAS = 69696;         // slab stride (66*66*16)
constexpr int SRS = 1056;          // row stride (66*16)
constexpr size_t SVOL = 81ull * SAS;   // 5,645,376 elements

// tower volume: [11][66][66][160] channel-last (fp32 PA; fp16 PH_A/PH_B/PH_C)
constexpr int PZS = 696960;        // 4356*160
constexpr int PYS = 10560;         // 66*160
constexpr size_t PVOL = 11ull * 4356 * 160;  // 7,666,560

// workspace offsets (floats)
constexpr size_t OFF_MASK = 11290752;    // 81*4096
constexpr size_t OFF_INVM = 11622528;    // 4096
constexpr size_t OFF_SC   = 11626624;    // 36864
constexpr size_t OFF_YM   = 11663488;    // 1440
constexpr size_t OFF_Y2   = 11664928;    // 1440
constexpr size_t OFF_YMP  = 11666368;    // 46080
constexpr size_t OFF_PA   = 11712448;    // PVOL fp32 (residual base)
// ushort regions (element offsets from (ushort*)d_ws)
constexpr size_t UOFF_SHA = 0;                   // SVOL fp16 slice ping
constexpr size_t UOFF_SHB = 11290752;            // SVOL fp16 slice pong
constexpr size_t UOFF_PHC = 0;                   // PVOL fp16 (overlays dead slice bufs)
constexpr size_t UOFF_PHA = 38758016;            // PVOL fp16
constexpr size_t UOFF_PHB = 46424576;            // PVOL fp16
constexpr size_t UOFF_WH  = 54091136;            // 7*691200 tower weights (fp16)
constexpr size_t UOFF_WSH = 63767936;            // 19*2560 slice weights (fp16)
constexpr size_t UOFF_ABF = 63865216;            // 160*672 cost-B fp16

typedef float f32x4 __attribute__((ext_vector_type(4)));
typedef _Float16 h16x8 __attribute__((ext_vector_type(8)));
typedef _Float16 h16x4 __attribute__((ext_vector_type(4)));

__device__ __forceinline__ float lrelu_f(float v) { return v >= 0.f ? v : 0.1f * v; }

// ---------------- stage A: unshuffle + if0 conv + bn -> channel-last fp16 SHA ----------------
__global__ __launch_bounds__(256) void k_if0(const float* __restrict__ x,
                                             const float* __restrict__ w0,
                                             const float* __restrict__ bn0,
                                             _Float16* __restrict__ SHA) {
  int a = blockIdx.x;
  int p = blockIdx.y * 256 + threadIdx.x;
  int y = p >> 6, xx = p & 63;
  int ai = a / 9, aj = a % 9;
  float v[3][3];
#pragma unroll
  for (int dy = 0; dy < 3; ++dy) {
    int gy = y + dy - 1;
#pragma unroll
    for (int dx = 0; dx < 3; ++dx) {
      int gx = xx + dx - 1;
      v[dy][dx] = (gy >= 0 && gy < 64 && gx >= 0 && gx < 64)
                      ? x[(ai * 64 + gy) * 576 + aj * 64 + gx] : 0.f;
    }
  }
  h16x8 o0, o1;
#pragma unroll
  for (int c = 0; c < 16; ++c) {
    float acc = 0.f;
#pragma unroll
    for (int t = 0; t < 9; ++t) acc += w0[c * 9 + t] * v[t / 3][t % 3];
    float g = bn0[c], b = bn0[16 + c], m = bn0[32 + c], vv = bn0[48 + c];
    float val = (acc - m) * (g * rsqrtf(vv + EPSB)) + b;
    if (c < 8) o0[c] = (_Float16)val;
    else       o1[c - 8] = (_Float16)val;
  }
  _Float16* dst = SHA + (size_t)a * SAS + (size_t)(y + 1) * SRS + (size_t)(xx + 1) * 16;
  *(h16x8*)&dst[0] = o0;
  *(h16x8*)&dst[8] = o1;
}

// ---------------- slice weight transform: -> fp16 [conv][co(16)][k=t*16+ci (160)] ----------------
__global__ __launch_bounds__(256) void k_wslice(const float* __restrict__ resb_w,
                                                const float* __restrict__ if1_w,
                                                const float* __restrict__ if2_w,
                                                const float* __restrict__ last_w,
                                                _Float16* __restrict__ WSH) {
  int c = blockIdx.x;  // 0..18
  for (int idx = threadIdx.x; idx < 2560; idx += 256) {
    int o = idx / 160, k = idx % 160;
    int t = k >> 4, ci = k & 15;
    float v = 0.f;
    if (t < 9) {
      if (c < 16)       v = resb_w[((size_t)c * 256 + o * 16 + ci) * 9 + t];
      else if (c == 16) v = if1_w[(size_t)(o * 16 + ci) * 9 + t];
      else if (c == 17) v = (o < 8) ? if2_w[(size_t)(o * 16 + ci) * 9 + t] : 0.f;
      else              v = (o < 8 && ci < 8) ? last_w[(size_t)(o * 8 + ci) * 9 + t] : 0.f;
    }
    WSH[c * 2560 + idx] = (_Float16)v;
  }
}

// ---------------- tower weight transform (coalesced): [co][ci][27] -> fp16 [t][co*160+ci] ----------------
__global__ __launch_bounds__(256) void k_wt7(const float* __restrict__ c1,
                                             const float* __restrict__ c2,
                                             const float* __restrict__ r3,
                                             const float* __restrict__ c3,
                                             _Float16* __restrict__ WH) {
  __shared__ float L[6912];
  int l = blockIdx.y;
  const float* w = (l == 0) ? c1 : (l == 1) ? c2 : (l < 6) ? r3 + (size_t)(l - 2) * 691200 : c3;
  size_t base = (size_t)blockIdx.x * 256;
  for (int i = threadIdx.x; i < 6912; i += 256) L[i] = w[base * 27 + i];
  __syncthreads();
  _Float16* wh = WH + (size_t)l * 691200;
  int r = (int)base + threadIdx.x;
#pragma unroll 1
  for (int t = 0; t < 27; ++t) {
    float v = L[threadIdx.x * 27 + t];
    wh[(size_t)t * 25600 + r] = (_Float16)v;
  }
}

// ---------------- cost-B: (sq_w . fuse_w) -> fp16 [o][k=uv*8+g (672)] ----------------
__global__ __launch_bounds__(192) void k_A(const float* __restrict__ sq_w,
                                           const float* __restrict__ fuse_w,
                                           _Float16* __restrict__ ABF) {
  int k = blockIdx.x;  // 0..671
  int o = threadIdx.x;
  if (o >= 160) return;
  float acc = 0.f;
  if (k < 648) {
    int uv = k >> 3, g = k & 7;
    for (int o2 = 0; o2 < 64; ++o2)
      acc += sq_w[(size_t)o * 512 + g * 64 + o2] * fuse_w[(size_t)(g * 64 + o2) * 81 + uv];
  }
  ABF[(size_t)o * 672 + k] = (_Float16)acc;
}

// ---------------- mask generation ----------------
__device__ __forceinline__ float img_at(const float* __restrict__ x, int i, int j, int yy, int xx) {
  if (yy < 0 || yy >= 64 || xx < 0 || xx >= 64) return 0.f;
  return x[(i * 64 + yy) * 576 + j * 64 + xx];
}

__global__ __launch_bounds__(256) void k_mask(const float* __restrict__ x,
                                              const float* __restrict__ disp,
                                              float* __restrict__ mask,
                                              float* __restrict__ invm) {
  int p = blockIdx.x * 256 + threadIdx.x;
  int y = p >> 6, xx = p & 63;
  float d = -disp[p];
  float ref = x[(4 * 64 + y) * 576 + 4 * 64 + xx];
  float ssum = 0.f;
  float xbase = (float)xx * (64.0f / 63.0f);
  float ybase = (float)y * (64.0f / 63.0f);
  for (int i = 0; i < 9; ++i) {
    float py = ybase + (float)(i - 4) * d - 0.5f;
    float y0f = floorf(py);
    float fy = py - y0f;
    int y0 = (int)y0f;
    for (int j = 0; j < 9; ++j) {
      float px = xbase + (float)(j - 4) * d - 0.5f;
      float x0f = floorf(px);
      float fx = px - x0f;
      int x0 = (int)x0f;
      float val = img_at(x, i, j, y0, x0) * (1.f - fx) * (1.f - fy)
                + img_at(x, i, j, y0, x0 + 1) * fx * (1.f - fy)
                + img_at(x, i, j, y0 + 1, x0) * (1.f - fx) * fy
                + img_at(x, i, j, y0 + 1, x0 + 1) * fx * fy;
      float diff = (i == 4 && j == 4) ? 0.f : fabsf(val - ref);
      float m = 1.f - diff;
      m = m * m;
      mask[(i * 9 + j) * 4096 + p] = m;
      ssum += m;
    }
  }
  invm[p] = 81.f / ssum;
}

// ---------------- single slice 3x3 conv (tail layers), fp16 state, 512 thr (8 waves) ----------------
template <bool BN, bool LRELU, int CO>
__global__ __launch_bounds__(512, 4) void k_cs(const _Float16* __restrict__ in,
                                               _Float16* __restrict__ out,
                                               const _Float16* __restrict__ wsh,
                                               const float* __restrict__ bnp) {
  __shared__ _Float16 Af[15840];   // [10 rows][66 px][24]
  int a = blockIdx.x, y0 = blockIdx.y * 8;
  int tid = threadIdx.x, lane = tid & 63, w = tid >> 6;   // w 0..7
  int lr = lane & 15, lq = lane >> 4;
  const _Float16* src = in + (size_t)a * SAS + (size_t)y0 * SRS;
  for (int it = tid; it < 1320; it += 512) {
    int row = it / 132, rem = it % 132;
    int px = rem >> 1, half = rem & 1;
    h16x8 g = *(const h16x8*)&src[row * SRS + px * 16 + half * 8];
    *(h16x8*)&Af[(row * 66 + px) * 24 + half * 8] = g;
  }
  __syncthreads();
  h16x8 bh[5];
#pragma unroll
  for (int ks = 0; ks < 5; ++ks)
    bh[ks] = *(const h16x8*)&wsh[lr * 160 + ks * 32 + lq * 8];
  int offk[5];
#pragma unroll
  for (int ks = 0; ks < 5; ++ks) {
    int t = ks * 2 + (lq >> 1);
    if (t > 8) t = 8;
    offk[ks] = ((t / 3) * 66 + (t % 3)) * 24 + (lq & 1) * 8;
  }
  f32x4 acc[4];
#pragma unroll
  for (int i = 0; i < 4; ++i) acc[i] = (f32x4){0.f, 0.f, 0.f, 0.f};
#pragma unroll
  for (int mf = 0; mf < 4; ++mf) {
    int gm = w * 4 + mf;
    int yl = gm >> 2, xq = gm & 3;
    int am = (yl * 66 + xq * 16 + lr) * 24;
#pragma unroll
    for (int ks = 0; ks < 5; ++ks) {
      h16x8 ah = *(const h16x8*)&Af[am + offk[ks]];
      acc[mf] = __builtin_amdgcn_mfma_f32_16x16x32_f16(ah, bh[ks], acc[mf], 0, 0, 0);
    }
  }
  int co = lr;
  bool coval = (CO == 16) || (co < CO);
  float sc = 1.f, sh = 0.f;
  if (BN && coval) {
    float g = bnp[co], b = bnp[CO + co], m = bnp[2 * CO + co], vv = bnp[3 * CO + co];
    sc = g * rsqrtf(vv + EPSB);
    sh = b - m * sc;
  }
#pragma unroll
  for (int mf = 0; mf < 4; ++mf) {
    int gm = w * 4 + mf;
    int yl = gm >> 2, xq = gm & 3;
    if (coval) {
#pragma unroll
      for (int r = 0; r < 4; ++r) {
        int x = xq * 16 + lq * 4 + r;
        float val = acc[mf][r] * sc + sh;
        if (LRELU) val = lrelu_f(val);
        size_t oo = (size_t)a * SAS + (size_t)(y0 + yl + 1) * SRS + (size_t)(x + 1) * 16 + co;
        out[oo] = (_Float16)val;
      }
    }
  }
}

// ---------------- fused residual block (512 thr, 8 waves): conv1 -> conv2 + residual ----------------
__global__ __launch_bounds__(512, 4) void k_cs2(const _Float16* __restrict__ in,
                                                _Float16* __restrict__ out,
                                                const _Float16* __restrict__ w1,
                                                const _Float16* __restrict__ w2,
                                                const float* __restrict__ bias,   // [32]: b1,b2
                                                const float* __restrict__ bnp) {  // [128]: bn1,bn2
  __shared__ _Float16 L1[12 * 66 * 24];   // input rows y0-2..y0+9
  __shared__ _Float16 L2[10 * 66 * 24];   // conv1-out rows y0-1..y0+8
  int a = blockIdx.x, y0 = blockIdx.y * 8;
  int tid = threadIdx.x, lane = tid & 63, w = tid >> 6;   // w 0..7
  int lr = lane & 15, lq = lane >> 4;
  for (int i = tid; i < 1980; i += 512) ((h16x8*)L2)[i] = (h16x8)(_Float16)0.f;
  const _Float16* src = in + (size_t)a * SAS;
  for (int it = tid; it < 1584; it += 512) {
    int sr = it / 132, rem = it % 132;
    int px = rem >> 1, half = rem & 1;
    int gyp = y0 - 1 + sr;   // padded row index
    h16x8 g = (h16x8)(_Float16)0.f;
    if (gyp >= 0 && gyp <= 65)
      g = *(const h16x8*)&src[(size_t)gyp * SRS + px * 16 + half * 8];
    *(h16x8*)&L1[(sr * 66 + px) * 24 + half * 8] = g;
  }
  __syncthreads();
  int offk[5];
#pragma unroll
  for (int ks = 0; ks < 5; ++ks) {
    int t = ks * 2 + (lq >> 1);
    if (t > 8) t = 8;
    offk[ks] = ((t / 3) * 66 + (t % 3)) * 24 + (lq & 1) * 8;
  }
  // ---- conv1: 40 m-frags over 8 waves, gm = w*5+mf
  {
    h16x8 bh[5];
#pragma unroll
    for (int ks = 0; ks < 5; ++ks)
      bh[ks] = *(const h16x8*)&w1[lr * 160 + ks * 32 + lq * 8];
    float g1 = bnp[lr], b1 = bnp[16 + lr], m1 = bnp[32 + lr], v1 = bnp[48 + lr];
    float sc1 = g1 * rsqrtf(v1 + EPSB);
    float sh1 = b1 - m1 * sc1 + bias[lr] * sc1;
#pragma unroll
    for (int mf = 0; mf < 5; ++mf) {
      int gm = w * 5 + mf;
      int yl = gm >> 2, xq = gm & 3;
      f32x4 acc = (f32x4){0.f, 0.f, 0.f, 0.f};
      int am = (yl * 66 + xq * 16 + lr) * 24;
#pragma unroll
      for (int ks = 0; ks < 5; ++ks) {
        h16x8 ah = *(const h16x8*)&L1[am + offk[ks]];
        acc = __builtin_amdgcn_mfma_f32_16x16x32_f16(ah, bh[ks], acc, 0, 0, 0);
      }
      int gy = y0 - 1 + yl;   // conv1-out global row
      if (gy >= 0 && gy <= 63) {
#pragma unroll
        for (int r = 0; r < 4; ++r) {
          int x = xq * 16 + lq * 4 + r;
          float val = lrelu_f(acc[r] * sc1 + sh1);
          L2[(yl * 66 + x + 1) * 24 + lr] = (_Float16)val;
        }
      }
    }
  }
  __syncthreads();
  // ---- conv2 + residual: 32 m-frags over 8 waves, gm = w*4+mf
  {
    h16x8 bh[5];
#pragma unroll
    for (int ks = 0; ks < 5; ++ks)
      bh[ks] = *(const h16x8*)&w2[lr * 160 + ks * 32 + lq * 8];
    float g2 = bnp[64 + lr], b2 = bnp[80 + lr], m2 = bnp[96 + lr], v2 = bnp[112 + lr];
    float sc2 = g2 * rsqrtf(v2 + EPSB);
    float sh2 = b2 - m2 * sc2 + bias[16 + lr] * sc2;
#pragma unroll
    for (int mf = 0; mf < 4; ++mf) {
      int gm = w * 4 + mf;
      int yl = gm >> 2, xq = gm & 3;
      f32x4 acc = (f32x4){0.f, 0.f, 0.f, 0.f};
      int am = (yl * 66 + xq * 16 + lr) * 24;
#pragma unroll
      for (int ks = 0; ks < 5; ++ks) {
        h16x8 ah = *(const h16x8*)&L2[am + offk[ks]];
        acc = __builtin_amdgcn_mfma_f32_16x16x32_f16(ah, bh[ks], acc, 0, 0, 0);
      }
#pragma unroll
      for (int r = 0; r < 4; ++r) {
        int x = xq * 16 + lq * 4 + r;
        float res = (float)L1[((yl + 2) * 66 + x + 1) * 24 + lr];
        float val = res + acc[r] * sc2 + sh2;
        out[(size_t)a * SAS + (size_t)(y0 + yl + 1) * SRS + (size_t)(x + 1) * 16 + lr] =
            (_Float16)val;
      }
    }
  }
}

// ---------------- fused cost volume + squeeze: 1-pass fp16 MFMA, 512 thr ----------------
__global__ __launch_bounds__(512, 4) void k_costsq(const _Float16* __restrict__ feat,
                                                   const float* __restrict__ mask,
                                                   const float* __restrict__ invm,
                                                   const _Float16* __restrict__ ABF,
                                                   const float* __restrict__ sq_bn,
                                                   _Float16* __restrict__ outPH) {
  __shared__ _Float16 Ahs[6144];   // [64 x][96 k]
  int dI = blockIdx.x, y = blockIdx.y;
  int dd = dI - 4;
  int tid = threadIdx.x, lane = tid & 63, w = tid >> 6;   // w 0..7
  int wm = w >> 1, wn = w & 1;    // wm 0..3 (16-row x quadrant), wn 0..1 (N half)
  int lr = lane & 15, lq = lane >> 4;
  f32x4 acc[5];
#pragma unroll
  for (int j = 0; j < 5; ++j) acc[j] = (f32x4){0.f, 0.f, 0.f, 0.f};

  for (int ch = 0; ch < 7; ++ch) {
    __syncthreads();
    for (int it = tid; it < 768; it += 512) {
      int xl = it / 12, uvL = it % 12;
      int uv = ch * 12 + uvL;
      h16x8 hv = (h16x8)(_Float16)0.f;
      if (uv < 81) {
        int u = uv / 9, v = uv % 9;
        int ys = y + (4 - u) * dd;
        int xs = xl + (4 - v) * dd;
        if (ys >= 0 && ys < 64 && xs >= 0 && xs < 64) {
          const _Float16* fp = feat + (size_t)uv * SAS + (size_t)(ys + 1) * SRS + (size_t)(xs + 1) * 16;
          h16x8 fv = *(const h16x8*)fp;
          float mv = mask[uv * 4096 + y * 64 + xl];
#pragma unroll
          for (int j = 0; j < 8; ++j) hv[j] = (_Float16)((float)fv[j] * mv);
        }
      }
      *(h16x8*)&Ahs[xl * 96 + uvL * 8] = hv;
    }
    __syncthreads();
#pragma unroll
    for (int kb = 0; kb < 3; ++kb) {
      int ka = kb * 32 + lq * 8;
      h16x8 a0 = *(const h16x8*)&Ahs[(wm * 16 + lr) * 96 + ka];
      int kg = ch * 96 + ka;
#pragma unroll
      for (int nf = 0; nf < 5; ++nf) {
        int n = wn * 80 + nf * 16 + lr;
        h16x8 bf = *(const h16x8*)&ABF[(size_t)n * 672 + kg];
        acc[nf] = __builtin_amdgcn_mfma_f32_16x16x32_f16(a0, bf, acc[nf], 0, 0, 0);
      }
    }
  }
#pragma unroll
  for (int nf = 0; nf < 5; ++nf) {
    int n = wn * 80 + nf * 16 + lr;
    float g = sq_bn[n], b = sq_bn[160 + n], m = sq_bn[320 + n], vv = sq_bn[480 + n];
    float sc = g * rsqrtf(vv + EPSB), sh = b - m * sc;
#pragma unroll
    for (int r = 0; r < 4; ++r) {
      int x = wm * 16 + lq * 4 + r;
      float val = acc[nf][r] * invm[y * 64 + x];
      val = val * sc + sh;
      val = lrelu_f(val);
      outPH[(size_t)(dI + 1) * PZS + (size_t)(y + 1) * PYS + (size_t)(x + 1) * 160 + n] =
          (_Float16)val;
    }
  }
}

// ---------------- tower: 1-pass fp16 MFMA 3x3x3 conv 160->160 (round-14 proven) ----------------
template <bool LRELU>
__global__ __launch_bounds__(320, 3) void k_mconv(const _Float16* __restrict__ in,
                                                  float* __restrict__ out32,
                                                  _Float16* __restrict__ out16,
                                                  const _Float16* __restrict__ wh,
                                                  const float* __restrict__ bnp) {
  __shared__ _Float16 Af[66 * 168];
  int bid = blockIdx.x;
  int swz = (bid & 7) * 72 + (bid >> 3);   // 576 blocks, bijective XCD chunking
  int z = swz / 64, y = swz % 64;
  int tid = threadIdx.x;
  int lane = tid & 63;
  int wn = tid >> 6;            // 0..4
  int lr = lane & 15;
  int lq = lane >> 4;

  f32x4 acc[4][2];
#pragma unroll
  for (int i = 0; i < 4; ++i)
#pragma unroll
    for (int j = 0; j < 2; ++j) acc[i][j] = (f32x4){0.f, 0.f, 0.f, 0.f};

  const _Float16* wbase = wh + (size_t)(wn * 32 + lr) * 160 + lq * 8;

#pragma unroll 1
  for (int dzy = 0; dzy < 9; ++dzy) {
    int dz = dzy / 3, dy = dzy % 3;
    const _Float16* src = in + (size_t)(z + dz) * PZS + (size_t)(y + dy) * PYS;
    __syncthreads();
    for (int v = tid; v < 1320; v += 320) {
      h16x8 g = *(const h16x8*)&src[(size_t)v * 8];
      int row = v / 20, col = (v % 20) * 8;
      *(h16x8*)&Af[row * 168 + col] = g;
    }
    __syncthreads();

#pragma unroll 1
    for (int dx = 0; dx < 3; ++dx) {
      const _Float16* wt = wbase + (size_t)(dzy * 3 + dx) * 25600;
      h16x8 bA[2], bB[2];
#pragma unroll
      for (int nf = 0; nf < 2; ++nf)
        bA[nf] = *(const h16x8*)&wt[(size_t)nf * 16 * 160];

      auto step = [&](int ks, h16x8 (&cur)[2], h16x8 (&nxt)[2], bool pre) {
        if (pre) {
#pragma unroll
          for (int nf = 0; nf < 2; ++nf)
            nxt[nf] = *(const h16x8*)&wt[(size_t)nf * 16 * 160 + (ks + 1) * 32];
        }
        h16x8 a0 = *(const h16x8*)&Af[(0 * 16 + lr + dx) * 168 + ks * 32 + lq * 8];
        h16x8 a1 = *(const h16x8*)&Af[(1 * 16 + lr + dx) * 168 + ks * 32 + lq * 8];
        h16x8 a2 = *(const h16x8*)&Af[(2 * 16 + lr + dx) * 168 + ks * 32 + lq * 8];
        h16x8 a3 = *(const h16x8*)&Af[(3 * 16 + lr + dx) * 168 + ks * 32 + lq * 8];
#pragma unroll
        for (int nf = 0; nf < 2; ++nf) {
          acc[0][nf] = __builtin_amdgcn_mfma_f32_16x16x32_f16(a0, cur[nf], acc[0][nf], 0, 0, 0);
          acc[1][nf] = __builtin_amdgcn_mfma_f32_16x16x32_f16(a1, cur[nf], acc[1][nf], 0, 0, 0);
          acc[2][nf] = __builtin_amdgcn_mfma_f32_16x16x32_f16(a2, cur[nf], acc[2][nf], 0, 0, 0);
          acc[3][nf] = __builtin_amdgcn_mfma_f32_16x16x32_f16(a3, cur[nf], acc[3][nf], 0, 0, 0);
        }
      };
      step(0, bA, bB, true);
      step(1, bB, bA, true);
      step(2, bA, bB, true);
      step(3, bB, bA, true);
      step(4, bA, bB, false);
    }
  }
  // epilogue
#pragma unroll
  for (int nf = 0; nf < 2; ++nf) {
    int n = wn * 32 + nf * 16 + lr;
    float sc = bnp[n] * rsqrtf(bnp[480 + n] + EPSB);
    float sh = bnp[160 + n] - bnp[320 + n] * sc;
#pragma unroll
    for (int mq = 0; mq < 4; ++mq) {
#pragma unroll
      for (int r = 0; r < 4; ++r) {
        int x = mq * 16 + lq * 4 + r;
        float val = acc[mq][nf][r] * sc + sh;
        if (LRELU) val = lrelu_f(val);
        size_t oo = (size_t)(z + 1) * PZS + (size_t)(y + 1) * PYS + (size_t)(x + 1) * 160 + n;
        if (out32) out32[oo] = val;
        if (out16) out16[oo] = (_Float16)val;
      }
    }
  }
}

// ---------------- c4: 160 -> 1 conv (fp16 in, fp32 math), 512 thr ----------------
__global__ __launch_bounds__(512) void k_c4(const _Float16* __restrict__ in,
                                            const float* __restrict__ w,
                                            float* __restrict__ score) {
  __shared__ float L[66 * 169];
  __shared__ float red[512];
  int zy = blockIdx.x;
  int z = zy / 64, y = zy % 64;
  int tid = threadIdx.x;
  int x = tid & 63, q = tid >> 6;   // q 0..7, 20 ci each
  float acc = 0.f;
  for (int dzy = 0; dzy < 9; ++dzy) {
    int dz = dzy / 3, dy = dzy % 3;
    const _Float16* src = in + (size_t)(z + dz) * PZS + (size_t)(y + dy) * PYS;
    __syncthreads();
    for (int v = tid; v < 1320; v += 512) {
      h16x8 g = *(const h16x8*)&src[v * 8];
      int row = v / 20, col = (v % 20) * 8;
#pragma unroll
      for (int j = 0; j < 8; ++j) L[row * 169 + col + j] = (float)g[j];
    }
    __syncthreads();
#pragma unroll 1
    for (int dx = 0; dx < 3; ++dx) {
      int t = dzy * 3 + dx;
      for (int ci = q * 20; ci < q * 20 + 20; ++ci)
        acc += L[(x + dx) * 169 + ci] * w[ci * 27 + t];
    }
  }
  red[tid] = acc;
  __syncthreads();
  if (q == 0) {
    float s = 0.f;
#pragma unroll
    for (int j = 0; j < 8; ++j) s += red[x + 64 * j];
    score[z * 4096 + y * 64 + x] = s;
  }
}

// ---------------- channel attention ----------------
__global__ __launch_bounds__(256) void k_mean1(const _Float16* __restrict__ in,
                                               float* __restrict__ ymp) {
  int z = blockIdx.x, yg = blockIdx.y, xq = blockIdx.z;
  int c = threadIdx.x;
  if (c >= 160) return;
  float s = 0.f;
  for (int yy = 0; yy < 8; ++yy) {
    int y = yg * 8 + yy;
    for (int xl = 0; xl < 16; ++xl) {
      int x = xq * 16 + xl;
      s += (float)in[(size_t)(z + 1) * PZS + (size_t)(y + 1) * PYS + (size_t)(x + 1) * 160 + c];
    }
  }
  ymp[((z * 8 + yg) * 4 + xq) * 160 + c] = s;
}

// fused mean2 + channel-attention MLP (one block, 256 threads)
__global__ __launch_bounds__(256) void k_ca2(const float* __restrict__ ymp,
                                             const float* __restrict__ w1,
                                             const float* __restrict__ b1,
                                             const float* __restrict__ bn1,
                                             const float* __restrict__ w2,
                                             const float* __restrict__ b2,
                                             const float* __restrict__ bn2,
                                             float* __restrict__ y2) {
  __shared__ float yml[1440];
  __shared__ float yy[90];
  for (int i = threadIdx.x; i < 1440; i += 256) {
    int c = i / 9, z = i % 9;
    float s = 0.f;
    for (int p = 0; p < 32; ++p) s += ymp[(z * 32 + p) * 160 + c];
    yml[i] = s * (1.f / 4096.f);
  }
  __syncthreads();
  if (threadIdx.x < 90) {
    int c = threadIdx.x / 9, z = threadIdx.x % 9;
    float acc = b1[c];
    for (int ci = 0; ci < 160; ++ci) acc += w1[c * 160 + ci] * yml[ci * 9 + z];
    float g = bn1[c], b = bn1[10 + c], m = bn1[20 + c], vv = bn1[30 + c];
    acc = (acc - m) * (g * rsqrtf(vv + EPSB)) + b;
    yy[threadIdx.x] = lrelu_f(acc);
  }
  __syncthreads();
  for (int i = threadIdx.x; i < 1440; i += 256) {
    int c = i / 9, z = i % 9;
    float acc = b2[c];
#pragma unroll
    for (int k = 0; k < 10; ++k) acc += w2[c * 10 + k] * yy[k * 9 + z];
    float g = bn2[c], b = bn2[160 + c], m = bn2[320 + c], vv = bn2[480 + c];
    acc = (acc - m) * (g * rsqrtf(vv + EPSB)) + b;
    y2[i] = 1.f / (1.f + expf(-acc));
  }
}

// residual add: PA += t*y2 (t fp16), refresh fp16 shadow of PA
__global__ __launch_bounds__(256) void k_sadd(float* __restrict__ buf,
                                              _Float16* __restrict__ shadow,
                                              const _Float16* __restrict__ t,
                                              const float* __restrict__ y2) {
  int i = blockIdx.x * 256 + threadIdx.x;
  int p = i / 160, c = i % 160;
  int z = p >> 12, r = p & 4095;
  int y = r >> 6, x = r & 63;
  size_t a = (size_t)(z + 1) * PZS + (size_t)(y + 1) * PYS + (size_t)(x + 1) * 160 + c;
  float val = buf[a] + (float)t[a] * y2[c * 9 + z];
  buf[a] = val;
  shadow[a] = (_Float16)val;
}

// ---------------- softmax + expectation ----------------
__global__ __launch_bounds__(256) void k_out(const float* __restrict__ score,
                                             float* __restrict__ out) {
  int p = blockIdx.x * 256 + threadIdx.x;
  float v[9];
  float mx = -1e30f;
#pragma unroll
  for (int z = 0; z < 9; ++z) {
    v[z] = score[z * 4096 + p];
    mx = fmaxf(mx, v[z]);
  }
  float s = 0.f, r = 0.f;
#pragma unroll
  for (int z = 0; z < 9; ++z) {
    float e = expf(v[z] - mx);
    s += e;
    r += e * (float)(z - 4);
  }
  out[p] = r / s;
}

// ---------------- launch ----------------
extern "C" void kernel_launch(void* const* d_in, const int* in_sizes, int n_in,
                              void* d_out, int out_size, void* d_ws, size_t ws_size,
                              hipStream_t stream) {
  const float* X      = (const float*)d_in[0];
  const float* disp   = (const float*)d_in[1];
  const float* if_w0  = (const float*)d_in[2];
  const float* if_bn0 = (const float*)d_in[3];
  const float* resb_w = (const float*)d_in[4];
  const float* resb_b = (const float*)d_in[5];
  const float* resb_bn= (const float*)d_in[6];
  const float* if_w1  = (const float*)d_in[7];
  const float* if_bn1 = (const float*)d_in[8];
  const float* if_w2  = (const float*)d_in[9];
  const float* if_bn2 = (const float*)d_in[10];
  const float* last_w = (const float*)d_in[11];
  const float* fuse_w = (const float*)d_in[12];
  const float* sq_w   = (const float*)d_in[13];
  const float* sq_bn  = (const float*)d_in[14];
  const float* c1_w   = (const float*)d_in[15];
  const float* c1_bn  = (const float*)d_in[16];
  const float* c2_w   = (const float*)d_in[17];
  const float* c2_bn  = (const float*)d_in[18];
  const float* c3_w   = (const float*)d_in[19];
  const float* c3_bn  = (const float*)d_in[20];
  const float* c4_w   = (const float*)d_in[21];
  const float* r3_w   = (const float*)d_in[22];
  const float* r3_bn  = (const float*)d_in[23];
  const float* ca_w1  = (const float*)d_in[24];
  const float* ca_b1  = (const float*)d_in[25];
  const float* ca_bn1 = (const float*)d_in[26];
  const float* ca_w2  = (const float*)d_in[27];
  const float* ca_b2  = (const float*)d_in[28];
  const float* ca_bn2 = (const float*)d_in[29];

  float* ws   = (float*)d_ws;
  float* MASK = ws + OFF_MASK;
  float* INVM = ws + OFF_INVM;
  float* SC   = ws + OFF_SC;
  float* Y2   = ws + OFF_Y2;
  float* YMP  = ws + OFF_YMP;
  float* PA   = ws + OFF_PA;
  unsigned short* U   = (unsigned short*)d_ws;
  _Float16* SHA       = (_Float16*)(U + UOFF_SHA);
  _Float16* SHB       = (_Float16*)(U + UOFF_SHB);
  _Float16* PHC       = (_Float16*)(U + UOFF_PHC);   // overlays SHA/SHB (dead after costsq)
  _Float16* PHA       = (_Float16*)(U + UOFF_PHA);
  _Float16* PHB       = (_Float16*)(U + UOFF_PHB);
  _Float16* WH        = (_Float16*)(U + UOFF_WH);
  _Float16* WSS       = (_Float16*)(U + UOFF_WSH);
  _Float16* ABF       = (_Float16*)(U + UOFF_ABF);

  hipMemsetAsync(SHA, 0, SVOL * 2, stream);
  hipMemsetAsync(SHB, 0, SVOL * 2, stream);
  hipMemsetAsync(PHA, 0, PVOL * 2, stream);
  hipMemsetAsync(PHB, 0, PVOL * 2, stream);

  k_wt7<<<dim3(100, 7), 256, 0, stream>>>(c1_w, c2_w, r3_w, c3_w, WH);
  k_wslice<<<19, 256, 0, stream>>>(resb_w, if_w1, if_w2, last_w, WSS);
  k_A<<<672, 192, 0, stream>>>(sq_w, fuse_w, ABF);
  k_mask<<<16, 256, 0, stream>>>(X, disp, MASK, INVM);

  k_if0<<<dim3(81, 16), 256, 0, stream>>>(X, if_w0, if_bn0, SHA);
  // 8 fused residual blocks, ping-pong SHA <-> SHB
  for (int i = 0; i < 8; ++i) {
    _Float16* src = (i & 1) ? SHB : SHA;
    _Float16* dst = (i & 1) ? SHA : SHB;
    k_cs2<<<dim3(81, 8), 512, 0, stream>>>(
        src, dst, WSS + (size_t)(2 * i) * 2560, WSS + (size_t)(2 * i + 1) * 2560,
        resb_b + i * 32, resb_bn + i * 128);
  }
  // after 8 blocks result is in SHA
  k_cs<true, true, 16><<<dim3(81, 8), 512, 0, stream>>>(SHA, SHB, WSS + 16 * 2560, if_bn1);
  k_cs<true, true, 8><<<dim3(81, 8), 512, 0, stream>>>(SHB, SHA, WSS + 17 * 2560, if_bn2);
  k_cs<false, false, 8><<<dim3(81, 8), 512, 0, stream>>>(SHA, SHB, WSS + 18 * 2560, nullptr);

  k_costsq<<<dim3(9, 64), 512, 0, stream>>>(SHB, MASK, INVM, ABF, sq_bn, PHA);

  // tower (fp16 state; fp32 only for residual base PA; PHC = branch scratch)
  k_mconv<true><<<576, 320, 0, stream>>>(PHA, nullptr, PHB, WH + 0ull * 691200, c1_bn);
  k_mconv<true><<<576, 320, 0, stream>>>(PHB, PA, PHA, WH + 1ull * 691200, c2_bn);
  for (int i = 0; i < 2; ++i) {
    k_mconv<true><<<576, 320, 0, stream>>>(PHA, nullptr, PHB,
                                           WH + (size_t)(2 + 2 * i) * 691200, r3_bn + i * 1280);
    k_mconv<false><<<576, 320, 0, stream>>>(PHB, nullptr, PHC,
                                            WH + (size_t)(3 + 2 * i) * 691200,
                                            r3_bn + i * 1280 + 640);
    k_mean1<<<dim3(9, 8, 4), 256, 0, stream>>>(PHC, YMP);
    k_ca2<<<1, 256, 0, stream>>>(YMP, ca_w1 + i * 1600, ca_b1 + i * 10, ca_bn1 + i * 40,
                                 ca_w2 + i * 1600, ca_b2 + i * 160, ca_bn2 + i * 640, Y2);
    k_sadd<<<23040, 256, 0, stream>>>(PA, PHA, PHC, Y2);
  }
  k_mconv<true><<<576, 320, 0, stream>>>(PHA, nullptr, PHB, WH + 6ull * 691200, c3_bn);
  k_c4<<<576, 512, 0, stream>>>(PHB, c4_w, SC);
  k_out<<<16, 256, 0, stream>>>(SC, (float*)d_out);
}

// Round 18
// 915.767 us; speedup vs baseline: 1.0186x; 1.0186x over previous
//
#include <hip/hip_runtime.h>
#include <hip/hip_bf16.h>
#include <math.h>

// ---------------- constants ----------------
constexpr float EPSB = 1e-5f;

// slice stage: channel-last padded [81][66][66][16] fp16
constexpr int SAS = 69696;         // slab stride (66*66*16)
constexpr int SRS = 1056;          // row stride (66*16)
constexpr size_t SVOL = 81ull * SAS;   // 5,645,376 elements

// tower volume: [11][66][66][160] channel-last (fp32 PA; fp16 PH_A/PH_B/PH_C)
constexpr int PZS = 696960;        // 4356*160
constexpr int PYS = 10560;         // 66*160
constexpr size_t PVOL = 11ull * 4356 * 160;  // 7,666,560

// workspace offsets (floats)
constexpr size_t OFF_MASK = 11290752;    // 81*4096
constexpr size_t OFF_INVM = 11622528;    // 4096
constexpr size_t OFF_SC   = 11626624;    // 36864
constexpr size_t OFF_YM   = 11663488;    // 1440
constexpr size_t OFF_Y2   = 11664928;    // 1440
constexpr size_t OFF_YMP  = 11666368;    // 46080
constexpr size_t OFF_PA   = 11712448;    // PVOL fp32 (residual base)
// ushort regions (element offsets from (ushort*)d_ws)
constexpr size_t UOFF_SHA = 0;                   // SVOL fp16 slice ping
constexpr size_t UOFF_SHB = 11290752;            // SVOL fp16 slice pong
constexpr size_t UOFF_PHC = 0;                   // PVOL fp16 (overlays dead slice bufs)
constexpr size_t UOFF_PHA = 38758016;            // PVOL fp16
constexpr size_t UOFF_PHB = 46424576;            // PVOL fp16
constexpr size_t UOFF_WH  = 54091136;            // 7*691200 tower weights (fp16)
constexpr size_t UOFF_WSH = 63767936;            // 19*2560 slice weights (fp16)
constexpr size_t UOFF_ABF = 63865216;            // 160*672 cost-B fp16

typedef float f32x4 __attribute__((ext_vector_type(4)));
typedef _Float16 h16x8 __attribute__((ext_vector_type(8)));
typedef _Float16 h16x4 __attribute__((ext_vector_type(4)));

__device__ __forceinline__ float lrelu_f(float v) { return v >= 0.f ? v : 0.1f * v; }

// ---------------- stage A: unshuffle + if0 conv + bn -> channel-last fp16 SHA ----------------
__global__ __launch_bounds__(256) void k_if0(const float* __restrict__ x,
                                             const float* __restrict__ w0,
                                             const float* __restrict__ bn0,
                                             _Float16* __restrict__ SHA) {
  int a = blockIdx.x;
  int p = blockIdx.y * 256 + threadIdx.x;
  int y = p >> 6, xx = p & 63;
  int ai = a / 9, aj = a % 9;
  float v[3][3];
#pragma unroll
  for (int dy = 0; dy < 3; ++dy) {
    int gy = y + dy - 1;
#pragma unroll
    for (int dx = 0; dx < 3; ++dx) {
      int gx = xx + dx - 1;
      v[dy][dx] = (gy >= 0 && gy < 64 && gx >= 0 && gx < 64)
                      ? x[(ai * 64 + gy) * 576 + aj * 64 + gx] : 0.f;
    }
  }
  h16x8 o0, o1;
#pragma unroll
  for (int c = 0; c < 16; ++c) {
    float acc = 0.f;
#pragma unroll
    for (int t = 0; t < 9; ++t) acc += w0[c * 9 + t] * v[t / 3][t % 3];
    float g = bn0[c], b = bn0[16 + c], m = bn0[32 + c], vv = bn0[48 + c];
    float val = (acc - m) * (g * rsqrtf(vv + EPSB)) + b;
    if (c < 8) o0[c] = (_Float16)val;
    else       o1[c - 8] = (_Float16)val;
  }
  _Float16* dst = SHA + (size_t)a * SAS + (size_t)(y + 1) * SRS + (size_t)(xx + 1) * 16;
  *(h16x8*)&dst[0] = o0;
  *(h16x8*)&dst[8] = o1;
}

// ---------------- slice weight transform: -> fp16 [conv][co(16)][k=t*16+ci (160)] ----------------
__global__ __launch_bounds__(256) void k_wslice(const float* __restrict__ resb_w,
                                                const float* __restrict__ if1_w,
                                                const float* __restrict__ if2_w,
                                                const float* __restrict__ last_w,
                                                _Float16* __restrict__ WSH) {
  int c = blockIdx.x;  // 0..18
  for (int idx = threadIdx.x; idx < 2560; idx += 256) {
    int o = idx / 160, k = idx % 160;
    int t = k >> 4, ci = k & 15;
    float v = 0.f;
    if (t < 9) {
      if (c < 16)       v = resb_w[((size_t)c * 256 + o * 16 + ci) * 9 + t];
      else if (c == 16) v = if1_w[(size_t)(o * 16 + ci) * 9 + t];
      else if (c == 17) v = (o < 8) ? if2_w[(size_t)(o * 16 + ci) * 9 + t] : 0.f;
      else              v = (o < 8 && ci < 8) ? last_w[(size_t)(o * 8 + ci) * 9 + t] : 0.f;
    }
    WSH[c * 2560 + idx] = (_Float16)v;
  }
}

// ---------------- tower weight transform (coalesced): [co][ci][27] -> fp16 [t][co*160+ci] ----------------
__global__ __launch_bounds__(256) void k_wt7(const float* __restrict__ c1,
                                             const float* __restrict__ c2,
                                             const float* __restrict__ r3,
                                             const float* __restrict__ c3,
                                             _Float16* __restrict__ WH) {
  __shared__ float L[6912];
  int l = blockIdx.y;
  const float* w = (l == 0) ? c1 : (l == 1) ? c2 : (l < 6) ? r3 + (size_t)(l - 2) * 691200 : c3;
  size_t base = (size_t)blockIdx.x * 256;
  for (int i = threadIdx.x; i < 6912; i += 256) L[i] = w[base * 27 + i];
  __syncthreads();
  _Float16* wh = WH + (size_t)l * 691200;
  int r = (int)base + threadIdx.x;
#pragma unroll 1
  for (int t = 0; t < 27; ++t) {
    float v = L[threadIdx.x * 27 + t];
    wh[(size_t)t * 25600 + r] = (_Float16)v;
  }
}

// ---------------- cost-B: (sq_w . fuse_w) -> fp16 [o][k=uv*8+g (672)] ----------------
__global__ __launch_bounds__(192) void k_A(const float* __restrict__ sq_w,
                                           const float* __restrict__ fuse_w,
                                           _Float16* __restrict__ ABF) {
  int k = blockIdx.x;  // 0..671
  int o = threadIdx.x;
  if (o >= 160) return;
  float acc = 0.f;
  if (k < 648) {
    int uv = k >> 3, g = k & 7;
    for (int o2 = 0; o2 < 64; ++o2)
      acc += sq_w[(size_t)o * 512 + g * 64 + o2] * fuse_w[(size_t)(g * 64 + o2) * 81 + uv];
  }
  ABF[(size_t)o * 672 + k] = (_Float16)acc;
}

// ---------------- mask generation ----------------
__device__ __forceinline__ float img_at(const float* __restrict__ x, int i, int j, int yy, int xx) {
  if (yy < 0 || yy >= 64 || xx < 0 || xx >= 64) return 0.f;
  return x[(i * 64 + yy) * 576 + j * 64 + xx];
}

__global__ __launch_bounds__(256) void k_mask(const float* __restrict__ x,
                                              const float* __restrict__ disp,
                                              float* __restrict__ mask,
                                              float* __restrict__ invm) {
  int p = blockIdx.x * 256 + threadIdx.x;
  int y = p >> 6, xx = p & 63;
  float d = -disp[p];
  float ref = x[(4 * 64 + y) * 576 + 4 * 64 + xx];
  float ssum = 0.f;
  float xbase = (float)xx * (64.0f / 63.0f);
  float ybase = (float)y * (64.0f / 63.0f);
  for (int i = 0; i < 9; ++i) {
    float py = ybase + (float)(i - 4) * d - 0.5f;
    float y0f = floorf(py);
    float fy = py - y0f;
    int y0 = (int)y0f;
    for (int j = 0; j < 9; ++j) {
      float px = xbase + (float)(j - 4) * d - 0.5f;
      float x0f = floorf(px);
      float fx = px - x0f;
      int x0 = (int)x0f;
      float val = img_at(x, i, j, y0, x0) * (1.f - fx) * (1.f - fy)
                + img_at(x, i, j, y0, x0 + 1) * fx * (1.f - fy)
                + img_at(x, i, j, y0 + 1, x0) * (1.f - fx) * fy
                + img_at(x, i, j, y0 + 1, x0 + 1) * fx * fy;
      float diff = (i == 4 && j == 4) ? 0.f : fabsf(val - ref);
      float m = 1.f - diff;
      m = m * m;
      mask[(i * 9 + j) * 4096 + p] = m;
      ssum += m;
    }
  }
  invm[p] = 81.f / ssum;
}

// ---------------- single slice 3x3 conv (tail layers), fp16 state, 512 thr (8 waves) ----------------
template <bool BN, bool LRELU, int CO>
__global__ __launch_bounds__(512, 4) void k_cs(const _Float16* __restrict__ in,
                                               _Float16* __restrict__ out,
                                               const _Float16* __restrict__ wsh,
                                               const float* __restrict__ bnp) {
  __shared__ _Float16 Af[15840];   // [10 rows][66 px][24]
  int a = blockIdx.x, y0 = blockIdx.y * 8;
  int tid = threadIdx.x, lane = tid & 63, w = tid >> 6;   // w 0..7
  int lr = lane & 15, lq = lane >> 4;
  const _Float16* src = in + (size_t)a * SAS + (size_t)y0 * SRS;
  for (int it = tid; it < 1320; it += 512) {
    int row = it / 132, rem = it % 132;
    int px = rem >> 1, half = rem & 1;
    h16x8 g = *(const h16x8*)&src[row * SRS + px * 16 + half * 8];
    *(h16x8*)&Af[(row * 66 + px) * 24 + half * 8] = g;
  }
  __syncthreads();
  h16x8 bh[5];
#pragma unroll
  for (int ks = 0; ks < 5; ++ks)
    bh[ks] = *(const h16x8*)&wsh[lr * 160 + ks * 32 + lq * 8];
  int offk[5];
#pragma unroll
  for (int ks = 0; ks < 5; ++ks) {
    int t = ks * 2 + (lq >> 1);
    if (t > 8) t = 8;
    offk[ks] = ((t / 3) * 66 + (t % 3)) * 24 + (lq & 1) * 8;
  }
  f32x4 acc[4];
#pragma unroll
  for (int i = 0; i < 4; ++i) acc[i] = (f32x4){0.f, 0.f, 0.f, 0.f};
#pragma unroll
  for (int mf = 0; mf < 4; ++mf) {
    int gm = w * 4 + mf;
    int yl = gm >> 2, xq = gm & 3;
    int am = (yl * 66 + xq * 16 + lr) * 24;
#pragma unroll
    for (int ks = 0; ks < 5; ++ks) {
      h16x8 ah = *(const h16x8*)&Af[am + offk[ks]];
      acc[mf] = __builtin_amdgcn_mfma_f32_16x16x32_f16(ah, bh[ks], acc[mf], 0, 0, 0);
    }
  }
  int co = lr;
  bool coval = (CO == 16) || (co < CO);
  float sc = 1.f, sh = 0.f;
  if (BN && coval) {
    float g = bnp[co], b = bnp[CO + co], m = bnp[2 * CO + co], vv = bnp[3 * CO + co];
    sc = g * rsqrtf(vv + EPSB);
    sh = b - m * sc;
  }
#pragma unroll
  for (int mf = 0; mf < 4; ++mf) {
    int gm = w * 4 + mf;
    int yl = gm >> 2, xq = gm & 3;
    if (coval) {
#pragma unroll
      for (int r = 0; r < 4; ++r) {
        int x = xq * 16 + lq * 4 + r;
        float val = acc[mf][r] * sc + sh;
        if (LRELU) val = lrelu_f(val);
        size_t oo = (size_t)a * SAS + (size_t)(y0 + yl + 1) * SRS + (size_t)(x + 1) * 16 + co;
        out[oo] = (_Float16)val;
      }
    }
  }
}

// ---------------- fused residual block (512 thr, 8 waves): conv1 -> conv2 + residual ----------------
__global__ __launch_bounds__(512, 4) void k_cs2(const _Float16* __restrict__ in,
                                                _Float16* __restrict__ out,
                                                const _Float16* __restrict__ w1,
                                                const _Float16* __restrict__ w2,
                                                const float* __restrict__ bias,   // [32]: b1,b2
                                                const float* __restrict__ bnp) {  // [128]: bn1,bn2
  __shared__ _Float16 L1[12 * 66 * 24];   // input rows y0-2..y0+9
  __shared__ _Float16 L2[10 * 66 * 24];   // conv1-out rows y0-1..y0+8
  int a = blockIdx.x, y0 = blockIdx.y * 8;
  int tid = threadIdx.x, lane = tid & 63, w = tid >> 6;   // w 0..7
  int lr = lane & 15, lq = lane >> 4;
  for (int i = tid; i < 1980; i += 512) ((h16x8*)L2)[i] = (h16x8)(_Float16)0.f;
  const _Float16* src = in + (size_t)a * SAS;
  for (int it = tid; it < 1584; it += 512) {
    int sr = it / 132, rem = it % 132;
    int px = rem >> 1, half = rem & 1;
    int gyp = y0 - 1 + sr;   // padded row index
    h16x8 g = (h16x8)(_Float16)0.f;
    if (gyp >= 0 && gyp <= 65)
      g = *(const h16x8*)&src[(size_t)gyp * SRS + px * 16 + half * 8];
    *(h16x8*)&L1[(sr * 66 + px) * 24 + half * 8] = g;
  }
  __syncthreads();
  int offk[5];
#pragma unroll
  for (int ks = 0; ks < 5; ++ks) {
    int t = ks * 2 + (lq >> 1);
    if (t > 8) t = 8;
    offk[ks] = ((t / 3) * 66 + (t % 3)) * 24 + (lq & 1) * 8;
  }
  // ---- conv1: 40 m-frags over 8 waves, gm = w*5+mf
  {
    h16x8 bh[5];
#pragma unroll
    for (int ks = 0; ks < 5; ++ks)
      bh[ks] = *(const h16x8*)&w1[lr * 160 + ks * 32 + lq * 8];
    float g1 = bnp[lr], b1 = bnp[16 + lr], m1 = bnp[32 + lr], v1 = bnp[48 + lr];
    float sc1 = g1 * rsqrtf(v1 + EPSB);
    float sh1 = b1 - m1 * sc1 + bias[lr] * sc1;
#pragma unroll
    for (int mf = 0; mf < 5; ++mf) {
      int gm = w * 5 + mf;
      int yl = gm >> 2, xq = gm & 3;
      f32x4 acc = (f32x4){0.f, 0.f, 0.f, 0.f};
      int am = (yl * 66 + xq * 16 + lr) * 24;
#pragma unroll
      for (int ks = 0; ks < 5; ++ks) {
        h16x8 ah = *(const h16x8*)&L1[am + offk[ks]];
        acc = __builtin_amdgcn_mfma_f32_16x16x32_f16(ah, bh[ks], acc, 0, 0, 0);
      }
      int gy = y0 - 1 + yl;   // conv1-out global row
      if (gy >= 0 && gy <= 63) {
#pragma unroll
        for (int r = 0; r < 4; ++r) {
          int x = xq * 16 + lq * 4 + r;
          float val = lrelu_f(acc[r] * sc1 + sh1);
          L2[(yl * 66 + x + 1) * 24 + lr] = (_Float16)val;
        }
      }
    }
  }
  __syncthreads();
  // ---- conv2 + residual: 32 m-frags over 8 waves, gm = w*4+mf
  {
    h16x8 bh[5];
#pragma unroll
    for (int ks = 0; ks < 5; ++ks)
      bh[ks] = *(const h16x8*)&w2[lr * 160 + ks * 32 + lq * 8];
    float g2 = bnp[64 + lr], b2 = bnp[80 + lr], m2 = bnp[96 + lr], v2 = bnp[112 + lr];
    float sc2 = g2 * rsqrtf(v2 + EPSB);
    float sh2 = b2 - m2 * sc2 + bias[16 + lr] * sc2;
#pragma unroll
    for (int mf = 0; mf < 4; ++mf) {
      int gm = w * 4 + mf;
      int yl = gm >> 2, xq = gm & 3;
      f32x4 acc = (f32x4){0.f, 0.f, 0.f, 0.f};
      int am = (yl * 66 + xq * 16 + lr) * 24;
#pragma unroll
      for (int ks = 0; ks < 5; ++ks) {
        h16x8 ah = *(const h16x8*)&L2[am + offk[ks]];
        acc = __builtin_amdgcn_mfma_f32_16x16x32_f16(ah, bh[ks], acc, 0, 0, 0);
      }
#pragma unroll
      for (int r = 0; r < 4; ++r) {
        int x = xq * 16 + lq * 4 + r;
        float res = (float)L1[((yl + 2) * 66 + x + 1) * 24 + lr];
        float val = res + acc[r] * sc2 + sh2;
        out[(size_t)a * SAS + (size_t)(y0 + yl + 1) * SRS + (size_t)(x + 1) * 16 + lr] =
            (_Float16)val;
      }
    }
  }
}

// ---------------- fused cost volume + squeeze: 1-pass fp16 MFMA -> fp16 PHA ----------------
__global__ __launch_bounds__(256) void k_costsq(const _Float16* __restrict__ feat,
                                                const float* __restrict__ mask,
                                                const float* __restrict__ invm,
                                                const _Float16* __restrict__ ABF,
                                                const float* __restrict__ sq_bn,
                                                _Float16* __restrict__ outPH) {
  __shared__ _Float16 Ahs[6144];   // [64 x][96 k]
  int dI = blockIdx.x, y = blockIdx.y;
  int dd = dI - 4;
  int tid = threadIdx.x, lane = tid & 63, w = tid >> 6;
  int wm = w >> 1, wn = w & 1;
  int lr = lane & 15, lq = lane >> 4;
  f32x4 acc[2][5];
#pragma unroll
  for (int i = 0; i < 2; ++i)
#pragma unroll
    for (int j = 0; j < 5; ++j) acc[i][j] = (f32x4){0.f, 0.f, 0.f, 0.f};

  for (int ch = 0; ch < 7; ++ch) {
    __syncthreads();
    for (int it = tid; it < 768; it += 256) {
      int xl = it / 12, uvL = it % 12;
      int uv = ch * 12 + uvL;
      h16x8 hv = (h16x8)(_Float16)0.f;
      if (uv < 81) {
        int u = uv / 9, v = uv % 9;
        int ys = y + (4 - u) * dd;
        int xs = xl + (4 - v) * dd;
        if (ys >= 0 && ys < 64 && xs >= 0 && xs < 64) {
          const _Float16* fp = feat + (size_t)uv * SAS + (size_t)(ys + 1) * SRS + (size_t)(xs + 1) * 16;
          h16x8 fv = *(const h16x8*)fp;
          float mv = mask[uv * 4096 + y * 64 + xl];
#pragma unroll
          for (int j = 0; j < 8; ++j) hv[j] = (_Float16)((float)fv[j] * mv);
        }
      }
      *(h16x8*)&Ahs[xl * 96 + uvL * 8] = hv;
    }
    __syncthreads();
#pragma unroll
    for (int kb = 0; kb < 3; ++kb) {
      int ka = kb * 32 + lq * 8;
      h16x8 a0 = *(const h16x8*)&Ahs[(wm * 32 + lr) * 96 + ka];
      h16x8 a1 = *(const h16x8*)&Ahs[(wm * 32 + 16 + lr) * 96 + ka];
      int kg = ch * 96 + ka;
#pragma unroll
      for (int nf = 0; nf < 5; ++nf) {
        int n = wn * 80 + nf * 16 + lr;
        h16x8 bf = *(const h16x8*)&ABF[(size_t)n * 672 + kg];
        acc[0][nf] = __builtin_amdgcn_mfma_f32_16x16x32_f16(a0, bf, acc[0][nf], 0, 0, 0);
        acc[1][nf] = __builtin_amdgcn_mfma_f32_16x16x32_f16(a1, bf, acc[1][nf], 0, 0, 0);
      }
    }
  }
#pragma unroll
  for (int nf = 0; nf < 5; ++nf) {
    int n = wn * 80 + nf * 16 + lr;
    float g = sq_bn[n], b = sq_bn[160 + n], m = sq_bn[320 + n], vv = sq_bn[480 + n];
    float sc = g * rsqrtf(vv + EPSB), sh = b - m * sc;
#pragma unroll
    for (int mf = 0; mf < 2; ++mf) {
#pragma unroll
      for (int r = 0; r < 4; ++r) {
        int x = wm * 32 + mf * 16 + lq * 4 + r;
        float val = acc[mf][nf][r] * invm[y * 64 + x];
        val = val * sc + sh;
        val = lrelu_f(val);
        outPH[(size_t)(dI + 1) * PZS + (size_t)(y + 1) * PYS + (size_t)(x + 1) * 160 + n] =
            (_Float16)val;
      }
    }
  }
}

// ---------------- tower: 1-pass fp16 MFMA 3x3x3 conv 160->160 (round-14 proven) ----------------
template <bool LRELU>
__global__ __launch_bounds__(320, 3) void k_mconv(const _Float16* __restrict__ in,
                                                  float* __restrict__ out32,
                                                  _Float16* __restrict__ out16,
                                                  const _Float16* __restrict__ wh,
                                                  const float* __restrict__ bnp) {
  __shared__ _Float16 Af[66 * 168];
  int bid = blockIdx.x;
  int swz = (bid & 7) * 72 + (bid >> 3);   // 576 blocks, bijective XCD chunking
  int z = swz / 64, y = swz % 64;
  int tid = threadIdx.x;
  int lane = tid & 63;
  int wn = tid >> 6;            // 0..4
  int lr = lane & 15;
  int lq = lane >> 4;

  f32x4 acc[4][2];
#pragma unroll
  for (int i = 0; i < 4; ++i)
#pragma unroll
    for (int j = 0; j < 2; ++j) acc[i][j] = (f32x4){0.f, 0.f, 0.f, 0.f};

  const _Float16* wbase = wh + (size_t)(wn * 32 + lr) * 160 + lq * 8;

#pragma unroll 1
  for (int dzy = 0; dzy < 9; ++dzy) {
    int dz = dzy / 3, dy = dzy % 3;
    const _Float16* src = in + (size_t)(z + dz) * PZS + (size_t)(y + dy) * PYS;
    __syncthreads();
    for (int v = tid; v < 1320; v += 320) {
      h16x8 g = *(const h16x8*)&src[(size_t)v * 8];
      int row = v / 20, col = (v % 20) * 8;
      *(h16x8*)&Af[row * 168 + col] = g;
    }
    __syncthreads();

#pragma unroll 1
    for (int dx = 0; dx < 3; ++dx) {
      const _Float16* wt = wbase + (size_t)(dzy * 3 + dx) * 25600;
      h16x8 bA[2], bB[2];
#pragma unroll
      for (int nf = 0; nf < 2; ++nf)
        bA[nf] = *(const h16x8*)&wt[(size_t)nf * 16 * 160];

      auto step = [&](int ks, h16x8 (&cur)[2], h16x8 (&nxt)[2], bool pre) {
        if (pre) {
#pragma unroll
          for (int nf = 0; nf < 2; ++nf)
            nxt[nf] = *(const h16x8*)&wt[(size_t)nf * 16 * 160 + (ks + 1) * 32];
        }
        h16x8 a0 = *(const h16x8*)&Af[(0 * 16 + lr + dx) * 168 + ks * 32 + lq * 8];
        h16x8 a1 = *(const h16x8*)&Af[(1 * 16 + lr + dx) * 168 + ks * 32 + lq * 8];
        h16x8 a2 = *(const h16x8*)&Af[(2 * 16 + lr + dx) * 168 + ks * 32 + lq * 8];
        h16x8 a3 = *(const h16x8*)&Af[(3 * 16 + lr + dx) * 168 + ks * 32 + lq * 8];
#pragma unroll
        for (int nf = 0; nf < 2; ++nf) {
          acc[0][nf] = __builtin_amdgcn_mfma_f32_16x16x32_f16(a0, cur[nf], acc[0][nf], 0, 0, 0);
          acc[1][nf] = __builtin_amdgcn_mfma_f32_16x16x32_f16(a1, cur[nf], acc[1][nf], 0, 0, 0);
          acc[2][nf] = __builtin_amdgcn_mfma_f32_16x16x32_f16(a2, cur[nf], acc[2][nf], 0, 0, 0);
          acc[3][nf] = __builtin_amdgcn_mfma_f32_16x16x32_f16(a3, cur[nf], acc[3][nf], 0, 0, 0);
        }
      };
      step(0, bA, bB, true);
      step(1, bB, bA, true);
      step(2, bA, bB, true);
      step(3, bB, bA, true);
      step(4, bA, bB, false);
    }
  }
  // epilogue
#pragma unroll
  for (int nf = 0; nf < 2; ++nf) {
    int n = wn * 32 + nf * 16 + lr;
    float sc = bnp[n] * rsqrtf(bnp[480 + n] + EPSB);
    float sh = bnp[160 + n] - bnp[320 + n] * sc;
#pragma unroll
    for (int mq = 0; mq < 4; ++mq) {
#pragma unroll
      for (int r = 0; r < 4; ++r) {
        int x = mq * 16 + lq * 4 + r;
        float val = acc[mq][nf][r] * sc + sh;
        if (LRELU) val = lrelu_f(val);
        size_t oo = (size_t)(z + 1) * PZS + (size_t)(y + 1) * PYS + (size_t)(x + 1) * 160 + n;
        if (out32) out32[oo] = val;
        if (out16) out16[oo] = (_Float16)val;
      }
    }
  }
}

// ---------------- c4: 160 -> 1 conv (fp16 in, fp32 math) ----------------
__global__ __launch_bounds__(256) void k_c4(const _Float16* __restrict__ in,
                                            const float* __restrict__ w,
                                            float* __restrict__ score) {
  __shared__ float L[66 * 169];
  __shared__ float red[256];
  int zy = blockIdx.x;
  int z = zy / 64, y = zy % 64;
  int tid = threadIdx.x;
  int x = tid & 63, q = tid >> 6;
  float acc = 0.f;
  for (int dzy = 0; dzy < 9; ++dzy) {
    int dz = dzy / 3, dy = dzy % 3;
    const _Float16* src = in + (size_t)(z + dz) * PZS + (size_t)(y + dy) * PYS;
    __syncthreads();
    for (int v = tid; v < 1320; v += 256) {
      h16x8 g = *(const h16x8*)&src[v * 8];
      int row = v / 20, col = (v % 20) * 8;
#pragma unroll
      for (int j = 0; j < 8; ++j) L[row * 169 + col + j] = (float)g[j];
    }
    __syncthreads();
#pragma unroll 1
    for (int dx = 0; dx < 3; ++dx) {
      int t = dzy * 3 + dx;
      for (int ci = q * 40; ci < q * 40 + 40; ++ci)
        acc += L[(x + dx) * 169 + ci] * w[ci * 27 + t];
    }
  }
  red[tid] = acc;
  __syncthreads();
  if (q == 0)
    score[z * 4096 + y * 64 + x] = red[x] + red[64 + x] + red[128 + x] + red[192 + x];
}

// ---------------- channel attention ----------------
__global__ __launch_bounds__(256) void k_mean1(const _Float16* __restrict__ in,
                                               float* __restrict__ ymp) {
  int z = blockIdx.x, yg = blockIdx.y, xq = blockIdx.z;
  int c = threadIdx.x;
  if (c >= 160) return;
  float s = 0.f;
  for (int yy = 0; yy < 8; ++yy) {
    int y = yg * 8 + yy;
    for (int xl = 0; xl < 16; ++xl) {
      int x = xq * 16 + xl;
      s += (float)in[(size_t)(z + 1) * PZS + (size_t)(y + 1) * PYS + (size_t)(x + 1) * 160 + c];
    }
  }
  ymp[((z * 8 + yg) * 4 + xq) * 160 + c] = s;
}

__global__ __launch_bounds__(256) void k_mean2(const float* __restrict__ ymp,
                                               float* __restrict__ ym) {
  int idx = blockIdx.x * 256 + threadIdx.x;
  if (idx >= 1440) return;
  int c = idx / 9, z = idx % 9;
  float s = 0.f;
  for (int p = 0; p < 32; ++p) s += ymp[(z * 32 + p) * 160 + c];
  ym[idx] = s * (1.f / 4096.f);
}

__global__ __launch_bounds__(256) void k_ca(const float* __restrict__ ym,
                                            const float* __restrict__ w1,
                                            const float* __restrict__ b1,
                                            const float* __restrict__ bn1,
                                            const float* __restrict__ w2,
                                            const float* __restrict__ b2,
                                            const float* __restrict__ bn2,
                                            float* __restrict__ y2) {
  __shared__ float yml[1440];
  __shared__ float yy[90];
  for (int i = threadIdx.x; i < 1440; i += 256) yml[i] = ym[i];
  __syncthreads();
  if (threadIdx.x < 90) {
    int c = threadIdx.x / 9, z = threadIdx.x % 9;
    float acc = b1[c];
    for (int ci = 0; ci < 160; ++ci) acc += w1[c * 160 + ci] * yml[ci * 9 + z];
    float g = bn1[c], b = bn1[10 + c], m = bn1[20 + c], vv = bn1[30 + c];
    acc = (acc - m) * (g * rsqrtf(vv + EPSB)) + b;
    yy[threadIdx.x] = lrelu_f(acc);
  }
  __syncthreads();
  for (int i = threadIdx.x; i < 1440; i += 256) {
    int c = i / 9, z = i % 9;
    float acc = b2[c];
#pragma unroll
    for (int k = 0; k < 10; ++k) acc += w2[c * 10 + k] * yy[k * 9 + z];
    float g = bn2[c], b = bn2[160 + c], m = bn2[320 + c], vv = bn2[480 + c];
    acc = (acc - m) * (g * rsqrtf(vv + EPSB)) + b;
    y2[i] = 1.f / (1.f + expf(-acc));
  }
}

// residual add: PA += t*y2 (t fp16), refresh fp16 shadow of PA
__global__ __launch_bounds__(256) void k_sadd(float* __restrict__ buf,
                                              _Float16* __restrict__ shadow,
                                              const _Float16* __restrict__ t,
                                              const float* __restrict__ y2) {
  int i = blockIdx.x * 256 + threadIdx.x;
  int p = i / 160, c = i % 160;
  int z = p >> 12, r = p & 4095;
  int y = r >> 6, x = r & 63;
  size_t a = (size_t)(z + 1) * PZS + (size_t)(y + 1) * PYS + (size_t)(x + 1) * 160 + c;
  float val = buf[a] + (float)t[a] * y2[c * 9 + z];
  buf[a] = val;
  shadow[a] = (_Float16)val;
}

// ---------------- softmax + expectation ----------------
__global__ __launch_bounds__(256) void k_out(const float* __restrict__ score,
                                             float* __restrict__ out) {
  int p = blockIdx.x * 256 + threadIdx.x;
  float v[9];
  float mx = -1e30f;
#pragma unroll
  for (int z = 0; z < 9; ++z) {
    v[z] = score[z * 4096 + p];
    mx = fmaxf(mx, v[z]);
  }
  float s = 0.f, r = 0.f;
#pragma unroll
  for (int z = 0; z < 9; ++z) {
    float e = expf(v[z] - mx);
    s += e;
    r += e * (float)(z - 4);
  }
  out[p] = r / s;
}

// ---------------- launch ----------------
extern "C" void kernel_launch(void* const* d_in, const int* in_sizes, int n_in,
                              void* d_out, int out_size, void* d_ws, size_t ws_size,
                              hipStream_t stream) {
  const float* X      = (const float*)d_in[0];
  const float* disp   = (const float*)d_in[1];
  const float* if_w0  = (const float*)d_in[2];
  const float* if_bn0 = (const float*)d_in[3];
  const float* resb_w = (const float*)d_in[4];
  const float* resb_b = (const float*)d_in[5];
  const float* resb_bn= (const float*)d_in[6];
  const float* if_w1  = (const float*)d_in[7];
  const float* if_bn1 = (const float*)d_in[8];
  const float* if_w2  = (const float*)d_in[9];
  const float* if_bn2 = (const float*)d_in[10];
  const float* last_w = (const float*)d_in[11];
  const float* fuse_w = (const float*)d_in[12];
  const float* sq_w   = (const float*)d_in[13];
  const float* sq_bn  = (const float*)d_in[14];
  const float* c1_w   = (const float*)d_in[15];
  const float* c1_bn  = (const float*)d_in[16];
  const float* c2_w   = (const float*)d_in[17];
  const float* c2_bn  = (const float*)d_in[18];
  const float* c3_w   = (const float*)d_in[19];
  const float* c3_bn  = (const float*)d_in[20];
  const float* c4_w   = (const float*)d_in[21];
  const float* r3_w   = (const float*)d_in[22];
  const float* r3_bn  = (const float*)d_in[23];
  const float* ca_w1  = (const float*)d_in[24];
  const float* ca_b1  = (const float*)d_in[25];
  const float* ca_bn1 = (const float*)d_in[26];
  const float* ca_w2  = (const float*)d_in[27];
  const float* ca_b2  = (const float*)d_in[28];
  const float* ca_bn2 = (const float*)d_in[29];

  float* ws   = (float*)d_ws;
  float* MASK = ws + OFF_MASK;
  float* INVM = ws + OFF_INVM;
  float* SC   = ws + OFF_SC;
  float* YM   = ws + OFF_YM;
  float* Y2   = ws + OFF_Y2;
  float* YMP  = ws + OFF_YMP;
  float* PA   = ws + OFF_PA;
  unsigned short* U   = (unsigned short*)d_ws;
  _Float16* SHA       = (_Float16*)(U + UOFF_SHA);
  _Float16* SHB       = (_Float16*)(U + UOFF_SHB);
  _Float16* PHC       = (_Float16*)(U + UOFF_PHC);   // overlays SHA/SHB (dead after costsq)
  _Float16* PHA       = (_Float16*)(U + UOFF_PHA);
  _Float16* PHB       = (_Float16*)(U + UOFF_PHB);
  _Float16* WH        = (_Float16*)(U + UOFF_WH);
  _Float16* WSS       = (_Float16*)(U + UOFF_WSH);
  _Float16* ABF       = (_Float16*)(U + UOFF_ABF);

  hipMemsetAsync(SHA, 0, SVOL * 2, stream);
  hipMemsetAsync(SHB, 0, SVOL * 2, stream);
  hipMemsetAsync(PHA, 0, PVOL * 2, stream);
  hipMemsetAsync(PHB, 0, PVOL * 2, stream);

  k_wt7<<<dim3(100, 7), 256, 0, stream>>>(c1_w, c2_w, r3_w, c3_w, WH);
  k_wslice<<<19, 256, 0, stream>>>(resb_w, if_w1, if_w2, last_w, WSS);
  k_A<<<672, 192, 0, stream>>>(sq_w, fuse_w, ABF);
  k_mask<<<16, 256, 0, stream>>>(X, disp, MASK, INVM);

  k_if0<<<dim3(81, 16), 256, 0, stream>>>(X, if_w0, if_bn0, SHA);
  // 8 fused residual blocks, ping-pong SHA <-> SHB
  for (int i = 0; i < 8; ++i) {
    _Float16* src = (i & 1) ? SHB : SHA;
    _Float16* dst = (i & 1) ? SHA : SHB;
    k_cs2<<<dim3(81, 8), 512, 0, stream>>>(
        src, dst, WSS + (size_t)(2 * i) * 2560, WSS + (size_t)(2 * i + 1) * 2560,
        resb_b + i * 32, resb_bn + i * 128);
  }
  // after 8 blocks result is in SHA
  k_cs<true, true, 16><<<dim3(81, 8), 512, 0, stream>>>(SHA, SHB, WSS + 16 * 2560, if_bn1);
  k_cs<true, true, 8><<<dim3(81, 8), 512, 0, stream>>>(SHB, SHA, WSS + 17 * 2560, if_bn2);
  k_cs<false, false, 8><<<dim3(81, 8), 512, 0, stream>>>(SHA, SHB, WSS + 18 * 2560, nullptr);

  k_costsq<<<dim3(9, 64), 256, 0, stream>>>(SHB, MASK, INVM, ABF, sq_bn, PHA);

  // tower (fp16 state; fp32 only for residual base PA; PHC = branch scratch)
  k_mconv<true><<<576, 320, 0, stream>>>(PHA, nullptr, PHB, WH + 0ull * 691200, c1_bn);
  k_mconv<true><<<576, 320, 0, stream>>>(PHB, PA, PHA, WH + 1ull * 691200, c2_bn);
  for (int i = 0; i < 2; ++i) {
    k_mconv<true><<<576, 320, 0, stream>>>(PHA, nullptr, PHB,
                                           WH + (size_t)(2 + 2 * i) * 691200, r3_bn + i * 1280);
    k_mconv<false><<<576, 320, 0, stream>>>(PHB, nullptr, PHC,
                                            WH + (size_t)(3 + 2 * i) * 691200,
                                            r3_bn + i * 1280 + 640);
    k_mean1<<<dim3(9, 8, 4), 256, 0, stream>>>(PHC, YMP);
    k_mean2<<<6, 256, 0, stream>>>(YMP, YM);
    k_ca<<<1, 256, 0, stream>>>(YM, ca_w1 + i * 1600, ca_b1 + i * 10, ca_bn1 + i * 40,
                                ca_w2 + i * 1600, ca_b2 + i * 160, ca_bn2 + i * 640, Y2);
    k_sadd<<<23040, 256, 0, stream>>>(PA, PHA, PHC, Y2);
  }
  k_mconv<true><<<576, 320, 0, stream>>>(PHA, nullptr, PHB, WH + 6ull * 691200, c3_bn);
  k_c4<<<576, 256, 0, stream>>>(PHB, c4_w, SC);
  k_out<<<16, 256, 0, stream>>>(SC, (float*)d_out);
}